// Round 17
// baseline (285.644 us; speedup 1.0000x reference)
//
#include <hip/hip_runtime.h>
#include <stdint.h>

// ---------------- types ----------------
using i32x4 = __attribute__((ext_vector_type(4))) int;
using f32x4 = __attribute__((ext_vector_type(4))) float;
using f16x4 = __attribute__((ext_vector_type(4))) _Float16;

#define M_TOK 8192
#define N_EMB 1024
#define D_FF  4096

// ---------------- tiny init ----------------
__global__ void zero_slots_k(unsigned* s) {
  if (threadIdx.x < 16) s[threadIdx.x] = 0u;
}

// ---------------- fused global absmax over 3 buffers (blockIdx.y selects) ----------------
__global__ void absmax3_k(const float* __restrict__ p0, long n0,
                          const float* __restrict__ p1, long n1,
                          const float* __restrict__ p2, long n2,
                          unsigned* __restrict__ slots) {
  const float* p = blockIdx.y == 0 ? p0 : (blockIdx.y == 1 ? p1 : p2);
  long n = blockIdx.y == 0 ? n0 : (blockIdx.y == 1 ? n1 : n2);
  unsigned* slot = slots + blockIdx.y;

  long i = ((long)blockIdx.x * blockDim.x + threadIdx.x) * 4;
  long stride = (long)gridDim.x * blockDim.x * 4;
  float m = 0.f;
  for (; i < n; i += stride) {
    float4 v = *(const float4*)(p + i);
    m = fmaxf(m, fmaxf(fmaxf(fabsf(v.x), fabsf(v.y)), fmaxf(fabsf(v.z), fabsf(v.w))));
  }
  for (int o = 32; o; o >>= 1) m = fmaxf(m, __shfl_xor(m, o));
  __shared__ float sm[4];
  if ((threadIdx.x & 63) == 0) sm[threadIdx.x >> 6] = m;
  __syncthreads();
  if (threadIdx.x == 0) {
    m = fmaxf(fmaxf(sm[0], sm[1]), fmaxf(sm[2], sm[3]));
    atomicMax(slot, __float_as_uint(m));
  }
}

// ---------------- fused weight quant + MFMA-fragment packing (both matrices) ----------------
// Packed layout: P[tile][1024] where tile = mt*KT + kt covers rows [mt*16,mt*16+16) x
// k [kt*64, kt*64+64); byte l*16+j <-> W[mt*16 + (l&15)][kt*64 + (l>>4)*16 + j]
// == exact mfma_i32_16x16x64_i8 A/B fragment order (lane l reads its 16B directly).
__global__ void wquant_pack2_k(const float* __restrict__ W0, int8_t* __restrict__ P0, int K0,
                               const float* __restrict__ W1, int8_t* __restrict__ P1, int K1,
                               const unsigned* __restrict__ slots) {
  const float* W = blockIdx.y ? W1 : W0;
  int8_t* P = blockIdx.y ? P1 : P0;
  int K = blockIdx.y ? K1 : K0;
  float inv = 127.f / fmaxf(__uint_as_float(slots[blockIdx.y + 1]), 1e-8f);

  int tile = blockIdx.x * 4 + (threadIdx.x >> 6);
  int lane = threadIdx.x & 63;
  int KT = K >> 6;
  int mt = tile / KT, kt = tile % KT;
  const float* src = W + (long)(mt * 16 + (lane & 15)) * K + kt * 64 + (lane >> 4) * 16;

  int words[4];
#pragma unroll
  for (int j = 0; j < 4; j++) {
    float4 v = *(const float4*)(src + j * 4);
    int b0 = (int)fminf(fmaxf(rintf(v.x * inv), -127.f), 127.f);
    int b1 = (int)fminf(fmaxf(rintf(v.y * inv), -127.f), 127.f);
    int b2 = (int)fminf(fmaxf(rintf(v.z * inv), -127.f), 127.f);
    int b3 = (int)fminf(fmaxf(rintf(v.w * inv), -127.f), 127.f);
    words[j] = (b0 & 0xff) | ((b1 & 0xff) << 8) | ((b2 & 0xff) << 16) | ((b3 & 0xff) << 24);
  }
  i32x4 out; out[0] = words[0]; out[1] = words[1]; out[2] = words[2]; out[3] = words[3];
  *(i32x4*)(P + (long)tile * 1024 + lane * 16) = out;
}

// ---------------- pre-swizzle LoRA-down A[16][K] into per-lane MFMA B-fragments ----------------
__global__ void prep_bfrag_k(const float* __restrict__ A, _Float16* __restrict__ Bp, int K) {
  int s = blockIdx.x;
  int l = threadIdx.x;  // 64 threads
  int r = l & 15, g = l >> 4;
  float4 v = *(const float4*)(A + (long)r * K + s * 16 + g * 4);
  f16x4 h;
  h[0] = (_Float16)v.x; h[1] = (_Float16)v.y; h[2] = (_Float16)v.z; h[3] = (_Float16)v.w;
  *(f16x4*)(Bp + ((long)s * 64 + l) * 4) = h;
}

// ---------------- fused: quantize X rows (PACKED output) AND T = 2 * X @ A^T ----------------
// Block = 16 rows = exactly one packed row-tile (blockIdx.x). Packed store: the wave's
// 64 x 4B writes cover one contiguous 256B range (permuted within) -> coalesced.
__global__ __launch_bounds__(512) void lora_quant_k(
    const float* __restrict__ X, const _Float16* __restrict__ Bpre,
    const unsigned* __restrict__ slot, int8_t* __restrict__ Q,
    float* __restrict__ T, int K) {
  int lane = threadIdx.x & 63, wave = threadIdx.x >> 6;
  int row0 = blockIdx.x * 16;
  int r = lane & 15, g = threadIdx.x >> 4;  // global k-group (0..31)
  float inv = 127.f / fmaxf(__uint_as_float(*slot), 1e-8f);

  int kPerWave = K >> 3;
  int kbase = wave * kPerWave;
  const float* xrow = X + (long)(row0 + r) * K;
  int8_t* qtile = Q + (long)blockIdx.x * (K >> 6) * 1024;

  int gl = lane >> 4;  // k-subgroup within wave (0..3)
  f32x4 acc = {0.f, 0.f, 0.f, 0.f};
  int nsteps = kPerWave >> 4;
#pragma unroll 4
  for (int s = 0; s < nsteps; s++) {
    int k = kbase + s * 16 + gl * 4;
    float4 v = *(const float4*)(xrow + k);
    int b0 = (int)fminf(fmaxf(rintf(v.x * inv), -127.f), 127.f);
    int b1 = (int)fminf(fmaxf(rintf(v.y * inv), -127.f), 127.f);
    int b2 = (int)fminf(fmaxf(rintf(v.z * inv), -127.f), 127.f);
    int b3 = (int)fminf(fmaxf(rintf(v.w * inv), -127.f), 127.f);
    int w = (b0 & 0xff) | ((b1 & 0xff) << 8) | ((b2 & 0xff) << 16) | ((b3 & 0xff) << 24);
    // packed: tile k>>6, frag-lane = r + (((k>>4)&3)<<4), byte = frag-lane*16 + (k&15)
    long poff = (long)(k >> 6) * 1024 + ((r + (((k >> 4) & 3) << 4)) << 4) + (k & 15);
    *(int*)(qtile + poff) = w;
    f16x4 a;
    a[0] = (_Float16)v.x; a[1] = (_Float16)v.y; a[2] = (_Float16)v.z; a[3] = (_Float16)v.w;
    int gs = (kbase + s * 16) >> 4;
    f16x4 b = *(const f16x4*)(Bpre + ((long)gs * 64 + lane) * 4);
    acc = __builtin_amdgcn_mfma_f32_16x16x16f16(a, b, acc, 0, 0, 0);
  }

  __shared__ float part[8][16][17];
#pragma unroll
  for (int j = 0; j < 4; j++) part[wave][gl * 4 + j][r] = acc[j];
  __syncthreads();
  int t = threadIdx.x;
  if (t < 256) {
    int m = t >> 4, rr = t & 15;
    float sum = 0.f;
#pragma unroll
    for (int w = 0; w < 8; w++) sum += part[w][m][rr];
    T[(long)(row0 + m) * 16 + rr] = 2.0f * sum;  // LORA_SCALE = 32/16 = 2
  }
}

// ---------------- int8 GEMM: zero-sync streaming from packed fragments ----------------
// BM=256, BN=64, 256 thr (4 waves 2x2; per wave 8 m-frags x 2 n-frags = 128x32 output).
// NO LDS, NO barriers, NO explicit waitcnt: per k-tile, 10 coalesced 1KB dwordx4 loads
// (one packed fragment tile each, L2-resident) + 16 MFMA; compiler pipelines freely and
// waves proceed independently. This removes the gll->LDS->barrier feed shared by all
// prior variants (R7's no-LDS failure was uncoalesced LAYOUT, fixed here by packing).
template <bool GELU>
__global__ __launch_bounds__(256) void gemm_pk(
    const int8_t* __restrict__ Apk, const int8_t* __restrict__ Bpk,
    int N, int K,
    const unsigned* __restrict__ sa, const unsigned* __restrict__ sb,
    const float* __restrict__ bias,
    const float* __restrict__ T,   // [M][16], pre-scaled by LORA_SCALE
    const float* __restrict__ Bl,  // [N][16]
    float* __restrict__ C, unsigned* hmax) {
  // bijective XCD swizzle (nwg % 8 == 0 for both grids)
  int nwg = gridDim.x * gridDim.y;
  int lid = blockIdx.y * gridDim.x + blockIdx.x;
  int cpx = nwg >> 3;
  int nid = (lid & 7) * cpx + (lid >> 3);
  int bn = (nid % gridDim.x) * 64;
  int bm = (nid / gridDim.x) * 256;

  int t = threadIdx.x;
  int lane = t & 63, wave = t >> 6;
  int wr = wave >> 1, wc = wave & 1;
  int l16 = lane & 15, lq = lane >> 4;

  int KT = K >> 6;
  const int8_t* Ap = Apk + ((long)(bm >> 4) + wr * 8) * KT * 1024 + lane * 16;
  const int8_t* Bp = Bpk + ((long)(bn >> 4) + wc * 2) * KT * 1024 + lane * 16;

  i32x4 acc[8][2] = {};

#pragma unroll 2
  for (int kt = 0; kt < KT; ++kt) {
    i32x4 av[8], bv[2];
#pragma unroll
    for (int mf = 0; mf < 8; mf++)
      av[mf] = *(const i32x4*)(Ap + ((long)mf * KT + kt) * 1024);
#pragma unroll
    for (int nf = 0; nf < 2; nf++)
      bv[nf] = *(const i32x4*)(Bp + ((long)nf * KT + kt) * 1024);
#pragma unroll
    for (int mf = 0; mf < 8; mf++)
#pragma unroll
      for (int nf = 0; nf < 2; nf++)
        acc[mf][nf] = __builtin_amdgcn_mfma_i32_16x16x64_i8(av[mf], bv[nf], acc[mf][nf], 0, 0, 0);
  }

  // -------- epilogue --------
  float s = (fmaxf(__uint_as_float(*sa), 1e-8f) * (1.f / 127.f)) *
            (fmaxf(__uint_as_float(*sb), 1e-8f) * (1.f / 127.f));

  f16x4 af[8], bf[2];
#pragma unroll
  for (int mf = 0; mf < 8; mf++) {
    int m = bm + wr * 128 + mf * 16 + l16;
    float4 tv = *(const float4*)(T + (long)m * 16 + lq * 4);
    f16x4 v; v[0] = (_Float16)tv.x; v[1] = (_Float16)tv.y; v[2] = (_Float16)tv.z; v[3] = (_Float16)tv.w;
    af[mf] = v;
  }
#pragma unroll
  for (int nf = 0; nf < 2; nf++) {
    int n = bn + wc * 32 + nf * 16 + l16;
    float4 bv4 = *(const float4*)(Bl + (long)n * 16 + lq * 4);
    f16x4 v; v[0] = (_Float16)bv4.x; v[1] = (_Float16)bv4.y; v[2] = (_Float16)bv4.z; v[3] = (_Float16)bv4.w;
    bf[nf] = v;
  }
  float bias_v[2];
#pragma unroll
  for (int nf = 0; nf < 2; nf++) bias_v[nf] = bias[bn + wc * 32 + nf * 16 + l16];

  float lmax = 0.f;
#pragma unroll
  for (int mf = 0; mf < 8; mf++) {
#pragma unroll
    for (int nf = 0; nf < 2; nf++) {
      f32x4 fa = __builtin_amdgcn_mfma_f32_16x16x16f16(af[mf], bf[nf], f32x4{0.f, 0.f, 0.f, 0.f}, 0, 0, 0);
      int n = bn + wc * 32 + nf * 16 + l16;
#pragma unroll
      for (int j = 0; j < 4; j++) {
        int m = bm + wr * 128 + mf * 16 + lq * 4 + j;
        float v = s * (float)acc[mf][nf][j] + bias_v[nf] + fa[j];
        if constexpr (GELU) {
          v = 0.5f * v * (1.0f + erff(v * 0.70710678118654752f));
          lmax = fmaxf(lmax, fabsf(v));
        }
        C[(long)m * N + n] = v;
      }
    }
  }
  if constexpr (GELU) {
    for (int o = 32; o; o >>= 1) lmax = fmaxf(lmax, __shfl_xor(lmax, o));
    if (lane == 0) atomicMax(hmax, __float_as_uint(lmax));
  }
}

// ---------------- launch ----------------
extern "C" void kernel_launch(void* const* d_in, const int* in_sizes, int n_in,
                              void* d_out, int out_size, void* d_ws, size_t ws_size,
                              hipStream_t stream) {
  const float* x   = (const float*)d_in[0];
  const float* Wfc = (const float*)d_in[1];
  const float* bfc = (const float*)d_in[2];
  const float* Afc = (const float*)d_in[3];
  const float* Bfc = (const float*)d_in[4];
  const float* Wpj = (const float*)d_in[5];
  const float* bpj = (const float*)d_in[6];
  const float* Apj = (const float*)d_in[7];
  const float* Bpj = (const float*)d_in[8];
  float* out = (float*)d_out;

  char* ws = (char*)d_ws;
  unsigned* slots = (unsigned*)ws;  // [0]=max|x| [1]=max|Wfc| [2]=max|Wpj| [3]=max|h|
  int8_t* qx  = (int8_t*)(ws + 256);                 // packed [512][16][1024]
  int8_t* qwf = qx  + (size_t)M_TOK * N_EMB;         // packed [256][16][1024]
  int8_t* qwp = qwf + (size_t)D_FF * N_EMB;          // packed [64][64][1024]
  int8_t* qh  = qwp + (size_t)N_EMB * D_FF;          // packed [512][64][1024]
  float*  t1  = (float*)(qh + (size_t)M_TOK * D_FF);
  float*  t2  = t1  + (size_t)M_TOK * 16;
  _Float16* Bp1 = (_Float16*)(t2 + (size_t)M_TOK * 16);
  _Float16* Bp2 = Bp1 + (size_t)N_EMB * 16;
  float*  h   = (float*)(Bp2 + (size_t)D_FF * 16);

  zero_slots_k<<<1, 64, 0, stream>>>(slots);

  absmax3_k<<<dim3(1024, 3), 256, 0, stream>>>(
      x, (long)M_TOK * N_EMB, Wfc, (long)D_FF * N_EMB, Wpj, (long)N_EMB * D_FF, slots);

  // fused weight quant + fragment packing (4096 tiles each -> 1024 blocks x 2)
  wquant_pack2_k<<<dim3(1024, 2), 256, 0, stream>>>(
      Wfc, qwf, N_EMB, Wpj, qwp, D_FF, slots);

  prep_bfrag_k<<<N_EMB / 16, 64, 0, stream>>>(Afc, Bp1, N_EMB);
  prep_bfrag_k<<<D_FF / 16, 64, 0, stream>>>(Apj, Bp2, D_FF);

  lora_quant_k<<<M_TOK / 16, 512, 0, stream>>>(x, Bp1, slots + 0, qx, t1, N_EMB);

  // GEMM1: 256x64 tiles -> grid (64, 32) = 2048 blocks
  gemm_pk<true><<<dim3(D_FF / 64, M_TOK / 256), 256, 0, stream>>>(
      qx, qwf, D_FF, N_EMB, slots + 0, slots + 1, bfc, t1, Bfc, h, slots + 3);

  lora_quant_k<<<M_TOK / 16, 512, 0, stream>>>(h, Bp2, slots + 3, qh, t2, D_FF);

  // GEMM2: 256x64 tiles -> grid (16, 32) = 512 blocks
  gemm_pk<false><<<dim3(N_EMB / 64, M_TOK / 256), 256, 0, stream>>>(
      qh, qwp, N_EMB, D_FF, slots + 3, slots + 2, bpj, t2, Bpj, out, nullptr);
}

// Round 18
// 271.628 us; speedup vs baseline: 1.0516x; 1.0516x over previous
//
#include <hip/hip_runtime.h>
#include <stdint.h>

// ---------------- types ----------------
using i32x4 = __attribute__((ext_vector_type(4))) int;
using f32x4 = __attribute__((ext_vector_type(4))) float;
using f16x4 = __attribute__((ext_vector_type(4))) _Float16;

#define M_TOK 8192
#define N_EMB 1024
#define D_FF  4096

__device__ __forceinline__ void async_lds16(void* lds, const void* g) {
  __builtin_amdgcn_global_load_lds(
      (const __attribute__((address_space(1))) void*)g,
      (__attribute__((address_space(3))) void*)lds, 16, 0, 0);
}

// ---------------- tiny init ----------------
__global__ void zero_slots_k(unsigned* s) {
  if (threadIdx.x < 16) s[threadIdx.x] = 0u;
}

// ---------------- fused global absmax over 3 buffers (blockIdx.y selects) ----------------
__global__ void absmax3_k(const float* __restrict__ p0, long n0,
                          const float* __restrict__ p1, long n1,
                          const float* __restrict__ p2, long n2,
                          unsigned* __restrict__ slots) {
  const float* p = blockIdx.y == 0 ? p0 : (blockIdx.y == 1 ? p1 : p2);
  long n = blockIdx.y == 0 ? n0 : (blockIdx.y == 1 ? n1 : n2);
  unsigned* slot = slots + blockIdx.y;

  long i = ((long)blockIdx.x * blockDim.x + threadIdx.x) * 4;
  long stride = (long)gridDim.x * blockDim.x * 4;
  float m = 0.f;
  for (; i < n; i += stride) {
    float4 v = *(const float4*)(p + i);
    m = fmaxf(m, fmaxf(fmaxf(fabsf(v.x), fabsf(v.y)), fmaxf(fabsf(v.z), fabsf(v.w))));
  }
  for (int o = 32; o; o >>= 1) m = fmaxf(m, __shfl_xor(m, o));
  __shared__ float sm[4];
  if ((threadIdx.x & 63) == 0) sm[threadIdx.x >> 6] = m;
  __syncthreads();
  if (threadIdx.x == 0) {
    m = fmaxf(fmaxf(sm[0], sm[1]), fmaxf(sm[2], sm[3]));
    atomicMax(slot, __float_as_uint(m));
  }
}

// ---------------- fused int8 quantization of both weight matrices ----------------
__global__ void quant2_k(const float* __restrict__ p0, int8_t* __restrict__ q0, long n0,
                         const float* __restrict__ p1, int8_t* __restrict__ q1, long n1,
                         const unsigned* __restrict__ slots) {
  const float* p = blockIdx.y == 0 ? p0 : p1;
  int8_t* q = blockIdx.y == 0 ? q0 : q1;
  long n = blockIdx.y == 0 ? n0 : n1;
  float inv = 127.f / fmaxf(__uint_as_float(slots[blockIdx.y + 1]), 1e-8f);

  long i = ((long)blockIdx.x * blockDim.x + threadIdx.x) * 4;
  long stride = (long)gridDim.x * blockDim.x * 4;
  for (; i < n; i += stride) {
    float4 v = *(const float4*)(p + i);
    int b0 = (int)fminf(fmaxf(rintf(v.x * inv), -127.f), 127.f);
    int b1 = (int)fminf(fmaxf(rintf(v.y * inv), -127.f), 127.f);
    int b2 = (int)fminf(fmaxf(rintf(v.z * inv), -127.f), 127.f);
    int b3 = (int)fminf(fmaxf(rintf(v.w * inv), -127.f), 127.f);
    int w = (b0 & 0xff) | ((b1 & 0xff) << 8) | ((b2 & 0xff) << 16) | ((b3 & 0xff) << 24);
    *(int*)(q + i) = w;
  }
}

// ---------------- pre-swizzle LoRA-down A[16][K] into per-lane MFMA B-fragments ----------------
__global__ void prep_bfrag_k(const float* __restrict__ A, _Float16* __restrict__ Bp, int K) {
  int s = blockIdx.x;
  int l = threadIdx.x;  // 64 threads
  int r = l & 15, g = l >> 4;
  float4 v = *(const float4*)(A + (long)r * K + s * 16 + g * 4);
  f16x4 h;
  h[0] = (_Float16)v.x; h[1] = (_Float16)v.y; h[2] = (_Float16)v.z; h[3] = (_Float16)v.w;
  *(f16x4*)(Bp + ((long)s * 64 + l) * 4) = h;
}

// ---------------- fused: quantize X rows to int8 AND T = 2 * X @ A^T via f16 MFMA ----------------
__global__ __launch_bounds__(512) void lora_quant_k(
    const float* __restrict__ X, const _Float16* __restrict__ Bpre,
    const unsigned* __restrict__ slot, int8_t* __restrict__ Q,
    float* __restrict__ T, int K) {
  int lane = threadIdx.x & 63, wave = threadIdx.x >> 6;
  int row0 = blockIdx.x * 16;
  int r = lane & 15, g = lane >> 4;
  float inv = 127.f / fmaxf(__uint_as_float(*slot), 1e-8f);

  int kPerWave = K >> 3;
  int kbase = wave * kPerWave;
  const float* xrow = X + (long)(row0 + r) * K;
  int8_t* qrow = Q + (long)(row0 + r) * K;

  f32x4 acc = {0.f, 0.f, 0.f, 0.f};
  int nsteps = kPerWave >> 4;
#pragma unroll 4
  for (int s = 0; s < nsteps; s++) {
    int k = kbase + s * 16 + g * 4;
    float4 v = *(const float4*)(xrow + k);
    int b0 = (int)fminf(fmaxf(rintf(v.x * inv), -127.f), 127.f);
    int b1 = (int)fminf(fmaxf(rintf(v.y * inv), -127.f), 127.f);
    int b2 = (int)fminf(fmaxf(rintf(v.z * inv), -127.f), 127.f);
    int b3 = (int)fminf(fmaxf(rintf(v.w * inv), -127.f), 127.f);
    *(int*)(qrow + k) = (b0 & 0xff) | ((b1 & 0xff) << 8) | ((b2 & 0xff) << 16) | ((b3 & 0xff) << 24);
    f16x4 a;
    a[0] = (_Float16)v.x; a[1] = (_Float16)v.y; a[2] = (_Float16)v.z; a[3] = (_Float16)v.w;
    int gs = (kbase + s * 16) >> 4;
    f16x4 b = *(const f16x4*)(Bpre + ((long)gs * 64 + lane) * 4);
    acc = __builtin_amdgcn_mfma_f32_16x16x16f16(a, b, acc, 0, 0, 0);
  }

  __shared__ float part[8][16][17];
#pragma unroll
  for (int j = 0; j < 4; j++) part[wave][g * 4 + j][r] = acc[j];
  __syncthreads();
  int t = threadIdx.x;
  if (t < 256) {
    int m = t >> 4, rr = t & 15;
    float sum = 0.f;
#pragma unroll
    for (int w = 0; w < 8; w++) sum += part[w][m][rr];
    T[(long)(row0 + m) * 16 + rr] = 2.0f * sum;  // LORA_SCALE = 32/16 = 2
  }
}

// ---------------- int8 GEMM: R8 pipeline (measured best: 126us/GEMM) ----------------
// BM=256, BN=NF*64, BK=128, 512 thr / 8 waves (2M x 4N), per-wave 128 x NF*16.
// LDS: 2dbuf A(32KB) + 2dbuf B(NF*8KB) -> 128/96KB, 1 block/CU. XOR-swizzled LDS
// (slot c of row r at c^(r&7); inverse-permuted global source; frag reads 2-way = free).
// Pipeline per tile kt: p0 issue B(kt+1); 2 fat phases {8+NF ds_read, setprio-wrapped
// 32 MFMA}; barrier; issue A(kt+2) into kt's freed A buf; vmcnt(4) -> kt+1 landed,
// kt+2 A in flight (never drains mid-loop); barrier.
template <bool GELU, int NF>
__global__ __launch_bounds__(512) void gemm8p(
    const int8_t* __restrict__ Aq, const int8_t* __restrict__ Bq,
    int N, int K,
    const unsigned* __restrict__ sa, const unsigned* __restrict__ sb,
    const float* __restrict__ bias,
    const float* __restrict__ T,   // [M][16], pre-scaled by LORA_SCALE
    const float* __restrict__ Bl,  // [N][16]
    float* __restrict__ C, unsigned* hmax) {
  constexpr int BN = NF * 64;        // 256 or 128
  constexpr int BBUF = BN * 128;     // B bytes per K-tile
  __shared__ __align__(16) int8_t lds[65536 + 2 * BBUF];
  int8_t* ldsA = lds;                // 2 x 32768
  int8_t* ldsB = lds + 65536;        // 2 x BBUF

  // bijective XCD swizzle (nwg % 8 == 0 for both grids)
  int nwg = gridDim.x * gridDim.y;
  int lid = blockIdx.y * gridDim.x + blockIdx.x;
  int cpx = nwg >> 3;
  int nid = (lid & 7) * cpx + (lid >> 3);
  int bn = (nid % gridDim.x) * BN;
  int bm = (nid / gridDim.x) * 256;

  int t = threadIdx.x;
  int lane = t & 63, wave = t >> 6;
  int wr = wave >> 2, wc = wave & 3;          // 2 x 4 wave grid
  int l16 = lane & 15, lq = lane >> 4;

  const int8_t* gA = Aq + (long)bm * K;
  const int8_t* gB = Bq + (long)bn * K;

  // staging maps: slot s -> row=s>>3, lds col=s&7, global col=(s&7)^(row&7)
  int aDst[4], aSrc[4];
#pragma unroll
  for (int i = 0; i < 4; i++) {
    int s = i * 512 + t, row = s >> 3;
    aDst[i] = s * 16;
    aSrc[i] = row * K + (((s & 7) ^ (row & 7)) << 4);
  }
  int bDst[NF], bSrc[NF];
#pragma unroll
  for (int i = 0; i < NF; i++) {
    int s = i * 512 + t, row = s >> 3;
    bDst[i] = s * 16;
    bSrc[i] = row * K + (((s & 7) ^ (row & 7)) << 4);
  }

  // fragment read offsets (swizzled); k-half applied via ^ (ks<<6)
  int aoff[8], boff[NF];
#pragma unroll
  for (int mf = 0; mf < 8; mf++) {
    int row = wr * 128 + mf * 16 + l16;
    aoff[mf] = row * 128 + ((lq ^ (row & 7)) << 4);
  }
#pragma unroll
  for (int nf = 0; nf < NF; nf++) {
    int row = wc * (NF * 16) + nf * 16 + l16;
    boff[nf] = row * 128 + ((lq ^ (row & 7)) << 4);
  }

  i32x4 acc[8][NF] = {};
  int KT = K >> 7;

  // prologue: tile0 A+B, tile1 A. vmcnt(4) -> tile0 resident (tile1 A in flight).
#pragma unroll
  for (int i = 0; i < 4; i++) async_lds16(ldsA + aDst[i], gA + aSrc[i]);
#pragma unroll
  for (int i = 0; i < NF; i++) async_lds16(ldsB + bDst[i], gB + bSrc[i]);
#pragma unroll
  for (int i = 0; i < 4; i++) async_lds16(ldsA + 32768 + aDst[i], gA + aSrc[i] + 128);
  asm volatile("s_waitcnt vmcnt(4)" ::: "memory");
  __builtin_amdgcn_s_barrier();
  __builtin_amdgcn_sched_barrier(0);

  for (int kt = 0; kt < KT; ++kt) {
    const int8_t* Ab = ldsA + (kt & 1) * 32768;
    const int8_t* Bb = ldsB + (kt & 1) * BBUF;

    // p0: issue next tile's B loads into the other buffer
    if (kt + 1 < KT) {
      long ko = (long)(kt + 1) * 128;
      int nb = ((kt + 1) & 1) * BBUF;
#pragma unroll
      for (int i = 0; i < NF; i++) async_lds16(ldsB + nb + bDst[i], gB + bSrc[i] + ko);
    }

#pragma unroll
    for (int ks = 0; ks < 2; ks++) {
      int kx = ks << 6;
      i32x4 av[8], bv[NF];
#pragma unroll
      for (int mf = 0; mf < 8; mf++) av[mf] = *(const i32x4*)(Ab + (aoff[mf] ^ kx));
#pragma unroll
      for (int nf = 0; nf < NF; nf++) bv[nf] = *(const i32x4*)(Bb + (boff[nf] ^ kx));
      __builtin_amdgcn_s_setprio(1);
#pragma unroll
      for (int mf = 0; mf < 8; mf++)
#pragma unroll
        for (int nf = 0; nf < NF; nf++)
          acc[mf][nf] = __builtin_amdgcn_mfma_i32_16x16x64_i8(av[mf], bv[nf], acc[mf][nf], 0, 0, 0);
      __builtin_amdgcn_s_setprio(0);
    }

    __builtin_amdgcn_sched_barrier(0);
    __builtin_amdgcn_s_barrier();  // all waves done reading kt's buffers
    if (kt + 2 < KT) {
      long ko = (long)(kt + 2) * 128;
      int nb = (kt & 1) * 32768;   // kt's A buffer, now free
#pragma unroll
      for (int i = 0; i < 4; i++) async_lds16(ldsA + nb + aDst[i], gA + aSrc[i] + ko);
      asm volatile("s_waitcnt vmcnt(4)" ::: "memory");  // kt+1 fully landed; kt+2 A in flight
      __builtin_amdgcn_s_barrier();
      __builtin_amdgcn_sched_barrier(0);
    } else if (kt + 1 < KT) {
      asm volatile("s_waitcnt vmcnt(0)" ::: "memory");
      __builtin_amdgcn_s_barrier();
      __builtin_amdgcn_sched_barrier(0);
    }
  }

  // -------- epilogue --------
  float s = (fmaxf(__uint_as_float(*sa), 1e-8f) * (1.f / 127.f)) *
            (fmaxf(__uint_as_float(*sb), 1e-8f) * (1.f / 127.f));

  f16x4 af[8], bf[NF];
#pragma unroll
  for (int mf = 0; mf < 8; mf++) {
    int m = bm + wr * 128 + mf * 16 + l16;
    float4 tv = *(const float4*)(T + (long)m * 16 + lq * 4);
    f16x4 v; v[0] = (_Float16)tv.x; v[1] = (_Float16)tv.y; v[2] = (_Float16)tv.z; v[3] = (_Float16)tv.w;
    af[mf] = v;
  }
#pragma unroll
  for (int nf = 0; nf < NF; nf++) {
    int n = bn + wc * (NF * 16) + nf * 16 + l16;
    float4 bv4 = *(const float4*)(Bl + (long)n * 16 + lq * 4);
    f16x4 v; v[0] = (_Float16)bv4.x; v[1] = (_Float16)bv4.y; v[2] = (_Float16)bv4.z; v[3] = (_Float16)bv4.w;
    bf[nf] = v;
  }
  float bias_v[NF];
#pragma unroll
  for (int nf = 0; nf < NF; nf++) bias_v[nf] = bias[bn + wc * (NF * 16) + nf * 16 + l16];

  float lmax = 0.f;
#pragma unroll
  for (int mf = 0; mf < 8; mf++) {
#pragma unroll
    for (int nf = 0; nf < NF; nf++) {
      f32x4 fa = __builtin_amdgcn_mfma_f32_16x16x16f16(af[mf], bf[nf], f32x4{0.f, 0.f, 0.f, 0.f}, 0, 0, 0);
      int n = bn + wc * (NF * 16) + nf * 16 + l16;
#pragma unroll
      for (int j = 0; j < 4; j++) {
        int m = bm + wr * 128 + mf * 16 + lq * 4 + j;
        float v = s * (float)acc[mf][nf][j] + bias_v[nf] + fa[j];
        if constexpr (GELU) {
          v = 0.5f * v * (1.0f + erff(v * 0.70710678118654752f));
          lmax = fmaxf(lmax, fabsf(v));
        }
        C[(long)m * N + n] = v;
      }
    }
  }
  if constexpr (GELU) {
    for (int o = 32; o; o >>= 1) lmax = fmaxf(lmax, __shfl_xor(lmax, o));
    if (lane == 0) atomicMax(hmax, __float_as_uint(lmax));
  }
}

// ---------------- launch ----------------
extern "C" void kernel_launch(void* const* d_in, const int* in_sizes, int n_in,
                              void* d_out, int out_size, void* d_ws, size_t ws_size,
                              hipStream_t stream) {
  const float* x   = (const float*)d_in[0];
  const float* Wfc = (const float*)d_in[1];
  const float* bfc = (const float*)d_in[2];
  const float* Afc = (const float*)d_in[3];
  const float* Bfc = (const float*)d_in[4];
  const float* Wpj = (const float*)d_in[5];
  const float* bpj = (const float*)d_in[6];
  const float* Apj = (const float*)d_in[7];
  const float* Bpj = (const float*)d_in[8];
  float* out = (float*)d_out;

  char* ws = (char*)d_ws;
  unsigned* slots = (unsigned*)ws;  // [0]=max|x| [1]=max|Wfc| [2]=max|Wpj| [3]=max|h|
  int8_t* qx  = (int8_t*)(ws + 256);
  int8_t* qwf = qx  + (size_t)M_TOK * N_EMB;
  int8_t* qwp = qwf + (size_t)D_FF * N_EMB;
  int8_t* qh  = qwp + (size_t)N_EMB * D_FF;
  float*  t1  = (float*)(qh + (size_t)M_TOK * D_FF);
  float*  t2  = t1  + (size_t)M_TOK * 16;
  _Float16* Bp1 = (_Float16*)(t2 + (size_t)M_TOK * 16);
  _Float16* Bp2 = Bp1 + (size_t)N_EMB * 16;
  float*  h   = (float*)(Bp2 + (size_t)D_FF * 16);

  zero_slots_k<<<1, 64, 0, stream>>>(slots);

  // fused absmax over x, Wfc, Wpj (one launch, blockIdx.y selects buffer)
  absmax3_k<<<dim3(1024, 3), 256, 0, stream>>>(
      x, (long)M_TOK * N_EMB, Wfc, (long)D_FF * N_EMB, Wpj, (long)N_EMB * D_FF, slots);

  // fused weight quantization (one launch)
  quant2_k<<<dim3(2048, 2), 256, 0, stream>>>(
      Wfc, qwf, (long)D_FF * N_EMB, Wpj, qwp, (long)N_EMB * D_FF, slots);

  prep_bfrag_k<<<N_EMB / 16, 64, 0, stream>>>(Afc, Bp1, N_EMB);
  prep_bfrag_k<<<D_FF / 16, 64, 0, stream>>>(Apj, Bp2, D_FF);

  lora_quant_k<<<M_TOK / 16, 512, 0, stream>>>(x, Bp1, slots + 0, qx, t1, N_EMB);

  // GEMM1: 256x256 tiles -> grid (16, 32) = 512 blocks
  gemm8p<true, 4><<<dim3(D_FF / 256, M_TOK / 256), 512, 0, stream>>>(
      qx, qwf, D_FF, N_EMB, slots + 0, slots + 1, bfc, t1, Bfc, h, slots + 3);

  lora_quant_k<<<M_TOK / 16, 512, 0, stream>>>(h, Bp2, slots + 3, qh, t2, D_FF);

  // GEMM2: 256x128 tiles -> grid (8, 32) = 256 blocks
  gemm8p<false, 2><<<dim3(N_EMB / 128, M_TOK / 256), 512, 0, stream>>>(
      qh, qwp, N_EMB, D_FF, slots + 3, slots + 2, bpj, t2, Bpj, out, nullptr);
}